// Round 9
// baseline (8702.615 us; speedup 1.0000x reference)
//
#include <hip/hip_runtime.h>

// LSTMAutoEncoder: B=64, T=512, H=512, F=32.
// Dead-code: only encoder L0 (final h,c) and decoder L0 feed the output:
//   out[:, t, :] = h_dec0_before_step(511-t) @ W_out^T + b_out
// -> 1024 sequential cell steps; batch in 8 pods of 8 rows x 32 blocks.
//
// Round 9: in-wave full reduction (no block barrier, no Gr planes).
//  - Lane (kseg 0..7, rp 0..7) owns 2 gate rows (hidden j0+4w+(rp>>1);
//    even rp = {i,f}, odd rp = {g,o}) x K-slice h[64k,+64) + x[4k,+4).
//    Weights 2x17 f4v in VGPRs. Partials of each gate row live in ONE wave:
//    reduce = shfl_xor(8/16/32); activation via shfl_xor(1) + kseg-select;
//    owner (even-rp) lanes publish tagged {f32 h|u32 s+1} from registers.
//  - U block-shared, parity-2, skewed (+8 fl per 64-col seg, RP=580).
//    Each wave stages its own 128 cols chunk-wise (r8 tagged gather, order
//    0,4,1,5,... so GEMM rounds unlock in sequence); after ds_writes:
//    lgkmcnt(0) then LDS flag=s. GEMM rounds acquire-spin flags (intra-CU).
//    Flags bound intra-block skew < 2 steps -> parity-2 is race-free.
//  - Decoder out-proj: after GEMM all flags >= s, wave dots 2 batch rows x
//    all 512 cols vs Wo, 5x shfl_xor reduce, 1 store. No OPW LDS/combiner.

#define BB   64
#define TT   512
#define HH   512
#define FF   32
#define PODS 8
#define BT   8
#define GBLK 32
#define NTHR 256
#define NBLK (PODS * GBLK)
#define RP   580              // U row stride (512 + 7*8 skew pads + 12)
#define UPF  (BT * RP)        // 4640 floats per parity
#define UXW  (BT * FF)        // 256 floats per wave (x slice)
#define PUB_U64 (2 * PODS * BT * HH)   // 65536 u64 (512 KB in d_ws)

typedef float f4v __attribute__((ext_vector_type(4)));
typedef unsigned long long u64;

__device__ __forceinline__ float sigmf(float x)    { return 1.f / (1.f + __expf(-x)); }
__device__ __forceinline__ float tanhfast(float x) { return 1.f - 2.f / (__expf(2.f * x) + 1.f); }

// Lane (kseg, rp): gate rows gA = mA*512+j, gB = (mA+1)*512+j; K-slice
// h[64*kseg,+64) (16 f4v) + x[4*kseg,+4) (1 f4v).
__device__ __forceinline__ void load_w(
    const float* __restrict__ Wih, const float* __restrict__ Whh,
    const float* __restrict__ bih, const float* __restrict__ bhh,
    int j, int mA, int kseg, f4v wA[17], f4v wB[17], float& bA, float& bB)
{
  const int gA = mA * HH + j, gB = (mA + 1) * HH + j;
  #pragma unroll
  for (int kv = 0; kv < 16; ++kv) {
    wA[kv] = *(const f4v*)&Whh[gA * HH + 64 * kseg + 4 * kv];
    wB[kv] = *(const f4v*)&Whh[gB * HH + 64 * kseg + 4 * kv];
  }
  wA[16] = *(const f4v*)&Wih[gA * FF + 4 * kseg];
  wB[16] = *(const f4v*)&Wih[gB * FF + 4 * kseg];
  bA = bih[gA] + bhh[gA];
  bB = bih[gB] + bhh[gB];
}

__global__ void init_ws_kernel(u64* pub) {
  const int i = blockIdx.x * blockDim.x + threadIdx.x;
  if (i < PUB_U64) pub[i] = 0ull;   // h = 0.0f, tag = 0 (both parities)
}

#define LDU64(P) __hip_atomic_load((P), __ATOMIC_RELAXED, __HIP_MEMORY_SCOPE_AGENT)

// Stage chunk Q (own-wave cols 128w+16Q..+16): spin pub tags, write U (skewed),
// lgkmcnt(0), lane0 sets LDS flag = s. Prefetch chunk QN into slot QI+4.
#define STAGE(QI, Q, QN) do {                                                  \
    while ((unsigned)(va[QI] >> 32) < (unsigned)s ||                           \
           (unsigned)(vb[QI] >> 32) < (unsigned)s) {                           \
      __builtin_amdgcn_s_sleep(1);                                             \
      va[QI] = LDU64(gp + (Q) * 16);                                           \
      vb[QI] = LDU64(gp + (Q) * 16 + 8);                                       \
    }                                                                          \
    Uw[(Q) * 16 + 8 * ((Q) >> 2)]     = __uint_as_float((unsigned)va[QI]);     \
    Uw[(Q) * 16 + 8 * ((Q) >> 2) + 8] = __uint_as_float((unsigned)vb[QI]);     \
    asm volatile("s_waitcnt lgkmcnt(0)" ::: "memory");                         \
    if (lane == 0)                                                             \
      __hip_atomic_store(&fls[fbase + w * 8 + (Q)], s,                         \
                         __ATOMIC_RELAXED, __HIP_MEMORY_SCOPE_WORKGROUP);      \
    if ((QN) >= 0) {                                                           \
      va[((QI) + 4) & 7] = LDU64(gp + (QN) * 16);                              \
      vb[((QI) + 4) & 7] = LDU64(gp + (QN) * 16 + 8);                          \
    }                                                                          \
  } while (0)

// GEMM round RI: cols [64*kseg + 16*RI, +16) staged by wave kseg>>1 as chunk
// (kseg&1)*4+RI. Acquire-spin that flag, then 32 b128 reads x 8 FMA.
#define GROUND(RI) do {                                                        \
    const int fidx = fbase + (kseg >> 1) * 8 + (kseg & 1) * 4 + (RI);          \
    int fv = __hip_atomic_load(&fls[fidx], __ATOMIC_ACQUIRE,                   \
                               __HIP_MEMORY_SCOPE_WORKGROUP);                  \
    while (__any(fv < s))                                                      \
      fv = __hip_atomic_load(&fls[fidx], __ATOMIC_ACQUIRE,                     \
                             __HIP_MEMORY_SCOPE_WORKGROUP);                    \
    const float* Ur = Upar + 72 * kseg + 16 * (RI);                            \
    _Pragma("unroll")                                                          \
    for (int b = 0; b < 8; ++b) {                                              \
      _Pragma("unroll")                                                        \
      for (int v = 0; v < 4; ++v) {                                            \
        const f4v u = *(const f4v*)(Ur + b * RP + 4 * v);                      \
        const f4v wa = wA[4 * (RI) + v];                                       \
        const f4v wb2 = wB[4 * (RI) + v];                                      \
        accA[b] += u[0]*wa[0] + u[1]*wa[1] + u[2]*wa[2] + u[3]*wa[3];          \
        accB[b] += u[0]*wb2[0] + u[1]*wb2[1] + u[2]*wb2[2] + u[3]*wb2[3];      \
      }                                                                        \
    }                                                                          \
  } while (0)

__global__ void __launch_bounds__(NTHR, 1)
lstm_ae_kernel(const float* __restrict__ x,
               const float* __restrict__ eWih, const float* __restrict__ eWhh,
               const float* __restrict__ ebih, const float* __restrict__ ebhh,
               const float* __restrict__ dWih, const float* __restrict__ dWhh,
               const float* __restrict__ dbih, const float* __restrict__ dbhh,
               const float* __restrict__ Wo,  const float* __restrict__ bo,
               float* __restrict__ out, u64* __restrict__ pub)
{
  __shared__ float U[2 * UPF];     // [2][8][RP]  skewed h staging
  __shared__ float UX[4 * UXW];    // [4][8][32]  per-wave x slice
  __shared__ int   fls[64];        // [2][4][8]   staging flags

  const int tid = threadIdx.x;
  const int blk = blockIdx.x;
  const int pod = blk & (PODS - 1);
  const int gb  = blk >> 3;            // 0..31 within pod
  const int b0  = pod * BT;
  const int j0  = gb * 16;

  const int w    = tid >> 6;           // wave 0..3 (stages cols [128w,+128))
  const int lane = tid & 63;
  const int row  = lane >> 3;          // staging: batch row
  const int sub  = lane & 7;           // staging: col sub-offset
  const int kseg = lane >> 3;          // gemm: K-slice 0..7
  const int rp   = lane & 7;           // gemm: gate-row pair 0..7
  const int jl   = rp >> 1;
  const int mA   = (rp & 1) ? 2 : 0;   // even rp: {i,f}; odd rp: {g,o}
  const int jglob = j0 + 4 * w + jl;   // this lane's hidden index
  const bool owner = ((rp & 1) == 0);  // owns c[jglob][b=kseg]

  if (tid < 64) fls[tid] = -1;
  __syncthreads();   // once, outside the step loop

  f4v wA[17], wB[17];
  float bA, bB;
  load_w(eWih, eWhh, ebih, ebhh, jglob, mA, kseg, wA, wB, bA, bB);
  float c_reg = 0.f;

  #pragma unroll 1
  for (int phase = 0; phase < 2; ++phase) {
    #pragma unroll 1
    for (int step = 0; step < TT; ++step) {
      const int s = phase * TT + step;
      const int t = phase ? (TT - 1 - step) : step;
      const int par = s & 1;
      const u64* prd = pub + (size_t)(par * PODS + pod) * (BT * HH);
      u64*       pwr = pub + (size_t)(((s + 1) & 1) * PODS + pod) * (BT * HH);
      float* Upar = U + par * UPF;
      const int fbase = par * 32;

      // ---- stage own x slice (own-wave region, program-order safe) ----
      *(f4v*)&UX[w * UXW + row * FF + 4 * sub] =
          *(const f4v*)&x[((size_t)(b0 + row) * TT + t) * FF + 4 * sub];

      float accA[8], accB[8];
      #pragma unroll
      for (int b = 0; b < 8; ++b) {
        accA[b] = (kseg == 0) ? bA : 0.f;
        accB[b] = (kseg == 0) ? bB : 0.f;
      }

      // ---- interleaved: stage own chunks (order 0,4,1,5,2,6,3,7) + GEMM ----
      const u64* gp = prd + row * HH + 128 * w + sub;
      float* Uw = Upar + row * RP + 144 * w + sub;
      u64 va[8], vb[8];
      va[0] = LDU64(gp + 0);   vb[0] = LDU64(gp + 8);     // q=0
      va[1] = LDU64(gp + 64);  vb[1] = LDU64(gp + 72);    // q=4
      va[2] = LDU64(gp + 16);  vb[2] = LDU64(gp + 24);    // q=1
      va[3] = LDU64(gp + 80);  vb[3] = LDU64(gp + 88);    // q=5

      STAGE(0, 0, 2);  STAGE(1, 4, 6);  GROUND(0);
      STAGE(2, 1, 3);  STAGE(3, 5, 7);  GROUND(1);
      STAGE(4, 2, -1); STAGE(5, 6, -1); GROUND(2);
      STAGE(6, 3, -1); STAGE(7, 7, -1); GROUND(3);

      // ---- x part ----
      #pragma unroll
      for (int b = 0; b < 8; ++b) {
        const f4v u = *(const f4v*)&UX[w * UXW + b * FF + 4 * kseg];
        accA[b] += u[0]*wA[16][0] + u[1]*wA[16][1] + u[2]*wA[16][2] + u[3]*wA[16][3];
        accB[b] += u[0]*wB[16][0] + u[1]*wB[16][1] + u[2]*wB[16][2] + u[3]*wB[16][3];
      }

      // ---- in-wave K reduction (butterfly over kseg bits 8/16/32) ----
      #pragma unroll
      for (int b = 0; b < 8; ++b) {
        accA[b] += __shfl_xor(accA[b], 8);
        accA[b] += __shfl_xor(accA[b], 16);
        accA[b] += __shfl_xor(accA[b], 32);
        accB[b] += __shfl_xor(accB[b], 8);
        accB[b] += __shfl_xor(accB[b], 16);
        accB[b] += __shfl_xor(accB[b], 32);
      }
      // select own batch row b = kseg (static-index cndmask chain)
      float aA = accA[0], aB = accB[0];
      #pragma unroll
      for (int b = 1; b < 8; ++b) {
        if (kseg == b) { aA = accA[b]; aB = accB[b]; }
      }
      // exchange with row-pair partner: even lane gets (g,o), keeps (i,f)
      const float pg = __shfl_xor(aA, 1);
      const float po = __shfl_xor(aB, 1);
      if (owner) {
        const float c2 = sigmf(aB) * c_reg + sigmf(aA) * tanhfast(pg);
        const float h2 = sigmf(po) * tanhfast(c2);
        c_reg = c2;
        const u64 pk = ((u64)(unsigned)(s + 1) << 32) | (u64)__float_as_uint(h2);
        __hip_atomic_store(&pwr[kseg * HH + jglob], pk,
                           __ATOMIC_RELAXED, __HIP_MEMORY_SCOPE_AGENT);
      }

      // ---- decoder out-projection: wave handles batch rows {2w, 2w+1};
      // all flags >= s passed during GEMM -> full U[par] readable. Uses
      // pre-update h(t), faithful to reference. ----
      if (phase) {
        const int orow = 2 * w + (lane >> 5);
        const int cb   = (lane & 31) * 16;
        const float* Ur = Upar + orow * RP + cb + 8 * (cb >> 6);
        const float* Wr = Wo + gb * HH + cb;
        float pj = 0.f;
        #pragma unroll
        for (int k = 0; k < 16; k += 4) {
          const f4v u  = *(const f4v*)(Ur + k);
          const f4v wv = *(const f4v*)(Wr + k);
          pj += u[0]*wv[0] + u[1]*wv[1] + u[2]*wv[2] + u[3]*wv[3];
        }
        pj += __shfl_xor(pj, 1);
        pj += __shfl_xor(pj, 2);
        pj += __shfl_xor(pj, 4);
        pj += __shfl_xor(pj, 8);
        pj += __shfl_xor(pj, 16);
        if ((lane & 31) == 0)
          out[((size_t)(b0 + orow) * TT + t) * FF + gb] = pj + bo[gb];
      }
    }
    if (phase == 0)   // encoder done: swap register weights to decoder
      load_w(dWih, dWhh, dbih, dbhh, jglob, mA, kseg, wA, wB, bA, bB);
  }
}

extern "C" void kernel_launch(void* const* d_in, const int* in_sizes, int n_in,
                              void* d_out, int out_size, void* d_ws, size_t ws_size,
                              hipStream_t stream) {
  const float* x    = (const float*)d_in[0];
  const float* eWih = (const float*)d_in[1];   // enc_Wih0 [2048,32]
  const float* eWhh = (const float*)d_in[2];   // enc_Whh0 [2048,512]
  const float* ebih = (const float*)d_in[3];
  const float* ebhh = (const float*)d_in[4];
  // d_in[5..8] enc layer 1: dead (only feeds dead decoder layer 1)
  const float* dWih = (const float*)d_in[9];   // dec_Wih0
  const float* dWhh = (const float*)d_in[10];  // dec_Whh0
  const float* dbih = (const float*)d_in[11];
  const float* dbhh = (const float*)d_in[12];
  // d_in[13..16] dec layer 1: dead (hB/cB never reach outs)
  const float* Wo   = (const float*)d_in[17];  // [32,512]
  const float* bo   = (const float*)d_in[18];  // [32]
  float* out = (float*)d_out;

  u64* pubbuf = (u64*)d_ws;                    // [2][PODS][BT][HH] tagged h

  init_ws_kernel<<<dim3((PUB_U64 + NTHR - 1) / NTHR), dim3(NTHR), 0, stream>>>(pubbuf);
  lstm_ae_kernel<<<dim3(NBLK), dim3(NTHR), 0, stream>>>(
      x, eWih, eWhh, ebih, ebhh, dWih, dWhh, dbih, dbhh, Wo, bo,
      out, pubbuf);
}

// Round 10
// 6371.000 us; speedup vs baseline: 1.3660x; 1.3660x over previous
//
#include <hip/hip_runtime.h>

// LSTMAutoEncoder: B=64, T=512, H=512, F=32.
// Dead-code: only encoder L0 (final h,c) and decoder L0 feed the output:
//   out[:, t, :] = h_dec0_before_step(511-t) @ W_out^T + b_out
// -> 1024 sequential cell steps; batch in 8 pods of 8 rows x 32 blocks.
//
// Round 10 = round 8 (best: wave-private gather, 1 barrier, Gr reduce,
// tagged {f32 h|u32 tag} publish) + 3 fixes for chunk-retry exposure:
//  - PAIR-chunks: 4 waits x 2 chunks -> 256 FMA insts per wait (~0.21us)
//    matches one retry round; prefetch depth 2 pairs.
//  - no-sleep fast retries (sleep only after 2 failed rounds).
//  - decoder out-proj moved POST-barrier (overlaps reduce/publish),
//    shfl-reduced to 8 floats/wave, combined one step later (parity-3 LDS;
//    epilogue handles the final step). Removes pre-BAR out-proj work.

#define BB   64
#define TT   512
#define HH   512
#define FF   32
#define KP   548              // U row stride (floats): 512 h + 32 x + pad
#define PODS 8
#define BT   8                // batch rows per pod
#define GBLK 32               // blocks per pod
#define JT   16               // hidden indices per block
#define NTHR 256
#define NBLK (PODS * GBLK)
#define GRS  66               // Gr batch-row stride (64 gates + 2 pad)
#define GPL  (BT * GRS + 2)   // 530: per-ks plane stride
#define GRF  (16 * GPL)       // 8480 floats per parity
#define U_FLOATS  (BT * KP)   // 4384
#define OP3F 32               // [4 waves][8 rows] out-proj partials per slot
#define LDS_FLOATS (U_FLOATS + 2 * GRF + 3 * OP3F)   // 21440 (85.8 KB)
#define LDS_BYTES  (LDS_FLOATS * 4)
#define PUB_U64  (2 * PODS * BT * HH)   // 65536 (512 KB in d_ws)

typedef float f4v __attribute__((ext_vector_type(4)));
typedef unsigned long long u64;

__device__ __forceinline__ float sigmf(float x)    { return 1.f / (1.f + __expf(-x)); }
__device__ __forceinline__ float tanhfast(float x) { return 1.f - 2.f / (__expf(2.f * x) + 1.f); }

// Thread (w, kap, gt) owns, for every chunk q=0..7, cols [128w+16q+4kap, +4)
// of the 4 gate rows {m*HH + j0 + gt} plus x-cols {8w+2kap, +1}.
__device__ __forceinline__ void load_w(
    const float* __restrict__ Wih, const float* __restrict__ Whh,
    const float* __restrict__ bih, const float* __restrict__ bhh,
    int j0, int w, int kap, int gt, f4v wv[4][8], float2 wx[4], float bias[4])
{
  #pragma unroll
  for (int m = 0; m < 4; ++m) {
    const int g = m * HH + j0 + gt;
    #pragma unroll
    for (int q = 0; q < 8; ++q)
      wv[m][q] = *(const f4v*)&Whh[g * HH + w * 128 + q * 16 + kap * 4];
    wx[m]   = *(const float2*)&Wih[g * FF + w * 8 + kap * 2];
    bias[m] = bih[g] + bhh[g];
  }
}

__global__ void init_ws_kernel(u64* pub) {
  const int i = blockIdx.x * blockDim.x + threadIdx.x;
  if (i < PUB_U64) pub[i] = 0ull;   // h = 0.0f, tag = 0 (both parities)
}

#define LDU64(P) __hip_atomic_load((P), __ATOMIC_RELAXED, __HIP_MEMORY_SCOPE_AGENT)

#define ISSUE(P) do {                                                          \
    vv[P][0] = LDU64(gp + 32 * (P));                                           \
    vv[P][1] = LDU64(gp + 32 * (P) + 8);                                       \
    vv[P][2] = LDU64(gp + 32 * (P) + 16);                                      \
    vv[P][3] = LDU64(gp + 32 * (P) + 24);                                      \
  } while (0)

// Wait pair P (chunks 2P,2P+1; cols [32P,+32)): selective fast re-load of the
// stale subset (sleep only after 2 failed rounds), then stage to U.
#define WAITPAIR(P) do {                                                       \
    unsigned rem = 0xFu; int tries = 0;                                        \
    while (rem) {                                                              \
      if ((rem & 1u) && (unsigned)(vv[P][0] >> 32) >= us) rem &= ~1u;          \
      if ((rem & 2u) && (unsigned)(vv[P][1] >> 32) >= us) rem &= ~2u;          \
      if ((rem & 4u) && (unsigned)(vv[P][2] >> 32) >= us) rem &= ~4u;          \
      if ((rem & 8u) && (unsigned)(vv[P][3] >> 32) >= us) rem &= ~8u;          \
      if (rem) {                                                               \
        if (++tries > 2) __builtin_amdgcn_s_sleep(1);                          \
        if (rem & 1u) vv[P][0] = LDU64(gp + 32 * (P));                         \
        if (rem & 2u) vv[P][1] = LDU64(gp + 32 * (P) + 8);                     \
        if (rem & 4u) vv[P][2] = LDU64(gp + 32 * (P) + 16);                    \
        if (rem & 8u) vv[P][3] = LDU64(gp + 32 * (P) + 24);                    \
      }                                                                        \
    }                                                                          \
    Uw[32 * (P)]      = __uint_as_float((unsigned)vv[P][0]);                   \
    Uw[32 * (P) + 8]  = __uint_as_float((unsigned)vv[P][1]);                   \
    Uw[32 * (P) + 16] = __uint_as_float((unsigned)vv[P][2]);                   \
    Uw[32 * (P) + 24] = __uint_as_float((unsigned)vv[P][3]);                   \
  } while (0)

// FMA on chunk Q: 8 rows x 4 cols x 4 gate types (reads 4-unique-address b128).
#define FMACHUNK(Q) do {                                                       \
    _Pragma("unroll")                                                          \
    for (int b = 0; b < 8; ++b) {                                              \
      const f4v u = *(const f4v*)&U[b * KP + w * 128 + 16 * (Q) + 4 * kap];    \
      _Pragma("unroll")                                                        \
      for (int m = 0; m < 4; ++m)                                              \
        acc[m][b] += u[0] * wv[m][Q][0] + u[1] * wv[m][Q][1]                   \
                   + u[2] * wv[m][Q][2] + u[3] * wv[m][Q][3];                  \
    }                                                                          \
  } while (0)

__global__ void __launch_bounds__(NTHR, 1)
lstm_ae_kernel(const float* __restrict__ x,
               const float* __restrict__ eWih, const float* __restrict__ eWhh,
               const float* __restrict__ ebih, const float* __restrict__ ebhh,
               const float* __restrict__ dWih, const float* __restrict__ dWhh,
               const float* __restrict__ dbih, const float* __restrict__ dbhh,
               const float* __restrict__ Wo,  const float* __restrict__ bo,
               float* __restrict__ out, u64* __restrict__ pub)
{
  extern __shared__ float lds[];
  float* U   = lds;                      // [BT][KP]      h | x_t (wave-private cols)
  float* Gr  = lds + U_FLOATS;           // [2][16][GPL]  K-split partials (parity)
  float* OP3 = lds + U_FLOATS + 2 * GRF; // [3][4][8]     out-proj partials (mod-3)

  const int tid = threadIdx.x;
  const int blk = blockIdx.x;
  const int pod = blk & (PODS - 1);
  const int gb  = blk >> 3;          // 0..31 within pod
  const int b0  = pod * BT;
  const int j0  = gb * JT;

  const int w    = tid >> 6;         // wave 0..3: owns h cols [128w,128w+128)
  const int lane = tid & 63;
  const int row  = lane >> 3;        // batch row 0..7
  const int sub  = lane & 7;         // col sub-offset within chunk

  const int ks  = tid >> 4;          // K-slice id 0..15 (Gr plane index)
  const int kap = ks & 3;            // chunk-column group 0..3
  const int gt  = tid & 15;          // hidden index within block

  // Update mapping (static across steps -> c stays in a register).
  const bool upd = tid < BT * JT;            // waves 0-1
  const int  ub  = tid >> 4, ujl = tid & 15;
  float c_reg = 0.f;

  f4v   wv[4][8];
  float2 wx[4];
  float bias[4];
  load_w(eWih, eWhh, ebih, ebhh, j0, w, kap, gt, wv, wx, bias);

  #pragma unroll 1
  for (int phase = 0; phase < 2; ++phase) {
    #pragma unroll 1
    for (int step = 0; step < TT; ++step) {
      const int s = phase * TT + step;       // global step 0..1023
      const unsigned us = (unsigned)s;
      const int t = phase ? (TT - 1 - step) : step;
      const u64* prd = pub + (size_t)((s & 1) * PODS + pod) * (BT * HH);
      u64*       pwr = pub + (size_t)(((s + 1) & 1) * PODS + pod) * (BT * HH);
      float* Grp = Gr + (s & 1) * GRF;

      // ---- stage this wave's x slice (latency overlaps first wait) ----
      U[row * KP + HH + w * 8 + sub] = x[((size_t)(b0 + row) * TT + t) * FF + w * 8 + sub];

      float acc[4][8];
      #pragma unroll
      for (int m = 0; m < 4; ++m)
        #pragma unroll
        for (int b = 0; b < 8; ++b) acc[m][b] = (ks == 0) ? bias[m] : 0.f;

      // ---- paired gather + GEMM pipeline (prefetch depth 2 pairs) ----
      const u64* gp = prd + row * HH + 128 * w + sub;
      float* Uw = U + row * KP + 128 * w + sub;
      u64 vv[4][4];
      ISSUE(0); ISSUE(1);
      WAITPAIR(0); ISSUE(2);
      asm volatile("" ::: "memory");
      FMACHUNK(0); FMACHUNK(1);
      WAITPAIR(1); ISSUE(3);
      asm volatile("" ::: "memory");
      FMACHUNK(2); FMACHUNK(3);
      WAITPAIR(2);
      asm volatile("" ::: "memory");
      FMACHUNK(4); FMACHUNK(5);
      WAITPAIR(3);
      asm volatile("" ::: "memory");
      FMACHUNK(6); FMACHUNK(7);

      // ---- x part ----
      #pragma unroll
      for (int b = 0; b < 8; ++b) {
        const float2 ux = *(const float2*)&U[b * KP + HH + w * 8 + 2 * kap];
        #pragma unroll
        for (int m = 0; m < 4; ++m)
          acc[m][b] += ux.x * wx[m].x + ux.y * wx[m].y;
      }
      {
        float* Gw = Grp + ks * GPL + gt;
        #pragma unroll
        for (int b = 0; b < 8; ++b)
          #pragma unroll
          for (int m = 0; m < 4; ++m)
            Gw[b * GRS + m * 16] = acc[m][b];
      }
      __syncthreads();   // BAR A (the only barrier): Gr complete

      // ---- reduce 16 K-split partials, activations, update, tagged publish ----
      if (upd) {
        const float* g0 = Grp + ub * GRS + ujl;
        float si = 0.f, sf = 0.f, sg = 0.f, so = 0.f;
        #pragma unroll
        for (int q = 0; q < 16; ++q) {
          const float* g = g0 + q * GPL;
          si += g[0]; sf += g[16]; sg += g[32]; so += g[48];
        }
        const float c2 = sigmf(sf) * c_reg + sigmf(si) * tanhfast(sg);
        const float h2 = sigmf(so) * tanhfast(c2);
        c_reg = c2;
        const u64 pk = ((u64)(unsigned)(s + 1) << 32) | (u64)__float_as_uint(h2);
        __hip_atomic_store(&pwr[ub * HH + j0 + ujl], pk,
                           __ATOMIC_RELAXED, __HIP_MEMORY_SCOPE_AGENT);
      }

      // ---- decoder out-projection, POST-barrier (overlaps reduce/publish).
      // Partial over this wave's own 128 U cols (pre-update h(t), faithful),
      // shfl-reduced over sub -> 8 floats/wave into OP3[s%3]; combined one
      // step later (BAR A of s+1 orders the writes; (s+1)%3 != (s-1)%3). ----
      if (phase) {
        const float* wrow = Wo + gb * HH + w * 128 + sub * 16;
        const float* urow = U + row * KP + w * 128 + sub * 16;
        float pj = 0.f;
        #pragma unroll
        for (int k = 0; k < 16; k += 4) {
          const f4v wvv = *(const f4v*)(wrow + k);
          const f4v uvv = *(const f4v*)(urow + k);
          pj += uvv[0] * wvv[0] + uvv[1] * wvv[1] + uvv[2] * wvv[2] + uvv[3] * wvv[3];
        }
        pj += __shfl_xor(pj, 1);
        pj += __shfl_xor(pj, 2);
        pj += __shfl_xor(pj, 4);
        if (sub == 0) OP3[(s % 3) * OP3F + w * 8 + row] = pj;
        // combine PREVIOUS decode step (t_prev = t+1)
        if (step > 0 && tid >= 192 && tid < 200) {
          const int b = tid - 192;
          const float* op = OP3 + ((s - 1) % 3) * OP3F + b;
          const float sm = op[0] + op[8] + op[16] + op[24];
          out[((size_t)(b0 + b) * TT + (t + 1)) * FF + gb] = sm + bo[gb];
        }
      }
    }
    if (phase == 0)  // encoder done: swap register weights to decoder
      load_w(dWih, dWhh, dbih, dbhh, j0, w, kap, gt, wv, wx, bias);
  }

  // ---- epilogue: combine the final decode step's out-proj (t = 0) ----
  __syncthreads();
  if (tid >= 192 && tid < 200) {
    const int b = tid - 192;
    const float* op = OP3 + ((2 * TT - 1) % 3) * OP3F + b;
    const float sm = op[0] + op[8] + op[16] + op[24];
    out[((size_t)(b0 + b) * TT + 0) * FF + gb] = sm + bo[gb];
  }
}

extern "C" void kernel_launch(void* const* d_in, const int* in_sizes, int n_in,
                              void* d_out, int out_size, void* d_ws, size_t ws_size,
                              hipStream_t stream) {
  const float* x    = (const float*)d_in[0];
  const float* eWih = (const float*)d_in[1];   // enc_Wih0 [2048,32]
  const float* eWhh = (const float*)d_in[2];   // enc_Whh0 [2048,512]
  const float* ebih = (const float*)d_in[3];
  const float* ebhh = (const float*)d_in[4];
  // d_in[5..8] enc layer 1: dead (only feeds dead decoder layer 1)
  const float* dWih = (const float*)d_in[9];   // dec_Wih0
  const float* dWhh = (const float*)d_in[10];  // dec_Whh0
  const float* dbih = (const float*)d_in[11];
  const float* dbhh = (const float*)d_in[12];
  // d_in[13..16] dec layer 1: dead (hB/cB never reach outs)
  const float* Wo   = (const float*)d_in[17];  // [32,512]
  const float* bo   = (const float*)d_in[18];  // [32]
  float* out = (float*)d_out;

  u64* pubbuf = (u64*)d_ws;                    // [2][PODS][BT][HH] tagged h

  hipFuncSetAttribute(reinterpret_cast<const void*>(lstm_ae_kernel),
                      hipFuncAttributeMaxDynamicSharedMemorySize, LDS_BYTES);

  init_ws_kernel<<<dim3((PUB_U64 + NTHR - 1) / NTHR), dim3(NTHR), 0, stream>>>(pubbuf);
  lstm_ae_kernel<<<dim3(NBLK), dim3(NTHR), LDS_BYTES, stream>>>(
      x, eWih, eWhh, ebih, ebhh, dWih, dWhh, dbih, dbhh, Wo, bo,
      out, pubbuf);
}

// Round 11
// 6055.669 us; speedup vs baseline: 1.4371x; 1.0521x over previous
//
#include <hip/hip_runtime.h>

// LSTMAutoEncoder: B=64, T=512, H=512, F=32.
// Dead-code: only encoder L0 (final h,c) and decoder L0 feed the output:
//   out[:, t, :] = h_dec0_before_step(511-t) @ W_out^T + b_out
// -> 1024 sequential cell steps; batch in 8 pods of 8 rows x 32 blocks.
//
// Round 11 = round 8 skeleton (8-chunk gather->FMA pipeline, 1 barrier,
// Gr reduce, tagged {f32 h|u32 tag} publish, post-barrier out-proj) +:
//  - cross-iteration EARLY ISSUE: chunks 0-3's loads for step s+1 are issued
//    at the end of step s (after publish) -> first MALL round trip overlaps
//    out-proj/loop-overhead instead of stalling the gather head.
//  - adjacent-col remap (chunk Q, lane sub -> cols {16Q+2sub,+1}): staging
//    becomes one ds_write_b64 per chunk (8 LDS writes/lane, was 16).
//  - GPL 530->536: Gr-write bank pattern uniformly 2-way (free) not 3-4-way.

#define BB   64
#define TT   512
#define HH   512
#define FF   32
#define KP   548              // U row stride (floats): 512 h + 32 x + pad
#define PODS 8
#define BT   8                // batch rows per pod
#define GBLK 32               // blocks per pod
#define JT   16               // hidden indices per block
#define NTHR 256
#define NBLK (PODS * GBLK)
#define GRS  66               // Gr batch-row stride (64 gates + 2 pad)
#define GPL  (BT * GRS + 8)   // 536: per-ks plane stride (2-way uniform banks)
#define GRF  (16 * GPL)       // 8576 floats per parity
#define U_FLOATS  (BT * KP)   // 4384
#define OP3F 32               // [4 waves][8 rows] out-proj partials per slot
#define LDS_FLOATS (U_FLOATS + 2 * GRF + 3 * OP3F)   // 21632 (86.5 KB)
#define LDS_BYTES  (LDS_FLOATS * 4)
#define PUB_U64  (2 * PODS * BT * HH)   // 65536 (512 KB in d_ws)

typedef float f4v __attribute__((ext_vector_type(4)));
typedef unsigned long long u64;

__device__ __forceinline__ float sigmf(float x)    { return 1.f / (1.f + __expf(-x)); }
__device__ __forceinline__ float tanhfast(float x) { return 1.f - 2.f / (__expf(2.f * x) + 1.f); }

// Thread (w, kap, gt) owns, for every chunk q=0..7, cols [128w+16q+4kap, +4)
// of the 4 gate rows {m*HH + j0 + gt} plus x-cols {8w+2kap, +1}.
__device__ __forceinline__ void load_w(
    const float* __restrict__ Wih, const float* __restrict__ Whh,
    const float* __restrict__ bih, const float* __restrict__ bhh,
    int j0, int w, int kap, int gt, f4v wv[4][8], float2 wx[4], float bias[4])
{
  #pragma unroll
  for (int m = 0; m < 4; ++m) {
    const int g = m * HH + j0 + gt;
    #pragma unroll
    for (int q = 0; q < 8; ++q)
      wv[m][q] = *(const f4v*)&Whh[g * HH + w * 128 + q * 16 + kap * 4];
    wx[m]   = *(const float2*)&Wih[g * FF + w * 8 + kap * 2];
    bias[m] = bih[g] + bhh[g];
  }
}

__global__ void init_ws_kernel(u64* pub) {
  const int i = blockIdx.x * blockDim.x + threadIdx.x;
  if (i < PUB_U64) pub[i] = 0ull;   // h = 0.0f, tag = 0 (both parities)
}

#define LDU64(P) __hip_atomic_load((P), __ATOMIC_RELAXED, __HIP_MEMORY_SCOPE_AGENT)

// Issue chunk Q's two tagged loads from base G (cols 16Q+2sub, +1).
#define ISSUE(Q, G) do {                                                       \
    va[Q] = LDU64((G) + 16 * (Q));                                             \
    vb[Q] = LDU64((G) + 16 * (Q) + 1);                                         \
  } while (0)

// Wait chunk Q fresh (tags >= s), fast retry (sleep after 2 rounds), then
// stage both cols with one ds_write_b64.
#define WAITCH(Q) do {                                                         \
    int tries = 0;                                                             \
    while ((unsigned)(va[Q] >> 32) < us || (unsigned)(vb[Q] >> 32) < us) {     \
      if (++tries > 2) __builtin_amdgcn_s_sleep(1);                            \
      va[Q] = LDU64(gp + 16 * (Q));                                            \
      vb[Q] = LDU64(gp + 16 * (Q) + 1);                                        \
    }                                                                          \
    float2 st_;                                                                \
    st_.x = __uint_as_float((unsigned)va[Q]);                                  \
    st_.y = __uint_as_float((unsigned)vb[Q]);                                  \
    *(float2*)&Us[16 * (Q)] = st_;                                             \
  } while (0)

// FMA on chunk Q: 8 rows x 4 cols x 4 gate types (4-unique-address b128 reads).
#define FMACHUNK(Q) do {                                                       \
    asm volatile("" ::: "memory");                                             \
    _Pragma("unroll")                                                          \
    for (int b = 0; b < 8; ++b) {                                              \
      const f4v u = *(const f4v*)&U[b * KP + w * 128 + 16 * (Q) + 4 * kap];    \
      _Pragma("unroll")                                                        \
      for (int m = 0; m < 4; ++m)                                              \
        acc[m][b] += u[0] * wv[m][Q][0] + u[1] * wv[m][Q][1]                   \
                   + u[2] * wv[m][Q][2] + u[3] * wv[m][Q][3];                  \
    }                                                                          \
  } while (0)

__global__ void __launch_bounds__(NTHR, 1)
lstm_ae_kernel(const float* __restrict__ x,
               const float* __restrict__ eWih, const float* __restrict__ eWhh,
               const float* __restrict__ ebih, const float* __restrict__ ebhh,
               const float* __restrict__ dWih, const float* __restrict__ dWhh,
               const float* __restrict__ dbih, const float* __restrict__ dbhh,
               const float* __restrict__ Wo,  const float* __restrict__ bo,
               float* __restrict__ out, u64* __restrict__ pub)
{
  extern __shared__ float lds[];
  float* U   = lds;                      // [BT][KP]      h | x_t (wave-private cols)
  float* Gr  = lds + U_FLOATS;           // [2][16][GPL]  K-split partials (parity)
  float* OP3 = lds + U_FLOATS + 2 * GRF; // [3][4][8]     out-proj partials (mod-3)

  const int tid = threadIdx.x;
  const int blk = blockIdx.x;
  const int pod = blk & (PODS - 1);
  const int gb  = blk >> 3;          // 0..31 within pod
  const int b0  = pod * BT;
  const int j0  = gb * JT;

  const int w    = tid >> 6;         // wave 0..3: owns h cols [128w,128w+128)
  const int lane = tid & 63;
  const int row  = lane >> 3;        // batch row 0..7
  const int sub  = lane & 7;         // col pair sub-offset within chunk

  const int ks  = tid >> 4;          // K-slice id 0..15 (Gr plane index)
  const int kap = ks & 3;            // chunk-column group 0..3
  const int gt  = tid & 15;          // hidden index within block

  // Update mapping (static across steps -> c stays in a register).
  const bool upd = tid < BT * JT;            // waves 0-1
  const int  ub  = tid >> 4, ujl = tid & 15;
  float c_reg = 0.f;

  f4v   wv[4][8];
  float2 wx[4];
  float bias[4];
  load_w(eWih, eWhh, ebih, ebhh, j0, w, kap, gt, wv, wx, bias);

  // Gather state persists across iterations (early-issued chunks 0-3).
  u64 va[8], vb[8];
  {
    const u64* g0 = pub + (size_t)pod * (BT * HH) + row * HH + 128 * w + 2 * sub;
    ISSUE(0, g0); ISSUE(1, g0); ISSUE(2, g0); ISSUE(3, g0);
  }

  #pragma unroll 1
  for (int phase = 0; phase < 2; ++phase) {
    #pragma unroll 1
    for (int step = 0; step < TT; ++step) {
      const int s = phase * TT + step;       // global step 0..1023
      const unsigned us = (unsigned)s;
      const int t = phase ? (TT - 1 - step) : step;
      const u64* prd = pub + (size_t)((s & 1) * PODS + pod) * (BT * HH);
      u64*       pwr = pub + (size_t)(((s + 1) & 1) * PODS + pod) * (BT * HH);
      float* Grp = Gr + (s & 1) * GRF;

      // ---- stage this wave's x slice (latency overlaps first wait) ----
      U[row * KP + HH + w * 8 + sub] =
          x[((size_t)(b0 + row) * TT + t) * FF + w * 8 + sub];

      float acc[4][8];
      #pragma unroll
      for (int m = 0; m < 4; ++m)
        #pragma unroll
        for (int b = 0; b < 8; ++b) acc[m][b] = (ks == 0) ? bias[m] : 0.f;

      // ---- 8-chunk gather->FMA pipeline (chunks 0-3 issued LAST step) ----
      const u64* gp = prd + row * HH + 128 * w + 2 * sub;
      float*     Us = U + row * KP + 128 * w + 2 * sub;

      WAITCH(0); ISSUE(4, gp); FMACHUNK(0);
      WAITCH(1); ISSUE(5, gp); FMACHUNK(1);
      WAITCH(2); ISSUE(6, gp); FMACHUNK(2);
      WAITCH(3); ISSUE(7, gp); FMACHUNK(3);
      WAITCH(4); FMACHUNK(4);
      WAITCH(5); FMACHUNK(5);
      WAITCH(6); FMACHUNK(6);
      WAITCH(7); FMACHUNK(7);

      // ---- x part ----
      #pragma unroll
      for (int b = 0; b < 8; ++b) {
        const float2 ux = *(const float2*)&U[b * KP + HH + w * 8 + 2 * kap];
        #pragma unroll
        for (int m = 0; m < 4; ++m)
          acc[m][b] += ux.x * wx[m].x + ux.y * wx[m].y;
      }
      {
        float* Gw = Grp + ks * GPL + gt;
        #pragma unroll
        for (int b = 0; b < 8; ++b)
          #pragma unroll
          for (int m = 0; m < 4; ++m)
            Gw[b * GRS + m * 16] = acc[m][b];
      }
      __syncthreads();   // BAR A (the only barrier): Gr complete

      // ---- reduce 16 K-split partials, activations, update, tagged publish ----
      if (upd) {
        const float* g0 = Grp + ub * GRS + ujl;
        float si = 0.f, sf = 0.f, sg = 0.f, so = 0.f;
        #pragma unroll
        for (int q = 0; q < 16; ++q) {
          const float* g = g0 + q * GPL;
          si += g[0]; sf += g[16]; sg += g[32]; so += g[48];
        }
        const float c2 = sigmf(sf) * c_reg + sigmf(si) * tanhfast(sg);
        const float h2 = sigmf(so) * tanhfast(c2);
        c_reg = c2;
        const u64 pk = ((u64)(unsigned)(s + 1) << 32) | (u64)__float_as_uint(h2);
        __hip_atomic_store(&pwr[ub * HH + j0 + ujl], pk,
                           __ATOMIC_RELAXED, __HIP_MEMORY_SCOPE_AGENT);
      }

      // ---- decoder out-projection, POST-barrier (overlaps reduce/publish).
      // Partial over this wave's own 128 U cols (pre-update h(t), faithful),
      // shfl-reduced over sub -> 8 floats/wave into OP3[s%3]; combined one
      // step later (BAR A of s+1 orders the writes; (s+1)%3 != (s-1)%3). ----
      if (phase) {
        const float* wrow = Wo + gb * HH + w * 128 + sub * 16;
        const float* urow = U + row * KP + w * 128 + sub * 16;
        float pj = 0.f;
        #pragma unroll
        for (int k = 0; k < 16; k += 4) {
          const f4v wvv = *(const f4v*)(wrow + k);
          const f4v uvv = *(const f4v*)(urow + k);
          pj += uvv[0] * wvv[0] + uvv[1] * wvv[1] + uvv[2] * wvv[2] + uvv[3] * wvv[3];
        }
        pj += __shfl_xor(pj, 1);
        pj += __shfl_xor(pj, 2);
        pj += __shfl_xor(pj, 4);
        if (sub == 0) OP3[(s % 3) * OP3F + w * 8 + row] = pj;
        // combine PREVIOUS decode step (t_prev = t+1)
        if (step > 0 && tid >= 192 && tid < 200) {
          const int b = tid - 192;
          const float* op = OP3 + ((s - 1) % 3) * OP3F + b;
          const float sm = op[0] + op[8] + op[16] + op[24];
          out[((size_t)(b0 + b) * TT + (t + 1)) * FF + gb] = sm + bo[gb];
        }
      }

      // ---- EARLY ISSUE: chunks 0-3 of step s+1 (next parity = pwr plane).
      // First MALL round trip flies during loop overhead / x staging; stale
      // arrivals simply retry in WAITCH. Compiler barrier pins placement. ----
      {
        const u64* gpn = (const u64*)pwr + row * HH + 128 * w + 2 * sub;
        ISSUE(0, gpn); ISSUE(1, gpn); ISSUE(2, gpn); ISSUE(3, gpn);
        asm volatile("" ::: "memory");
      }
    }
    if (phase == 0)  // encoder done: swap register weights to decoder
      load_w(dWih, dWhh, dbih, dbhh, j0, w, kap, gt, wv, wx, bias);
  }

  // ---- epilogue: combine the final decode step's out-proj (t = 0) ----
  __syncthreads();
  if (tid >= 192 && tid < 200) {
    const int b = tid - 192;
    const float* op = OP3 + ((2 * TT - 1) % 3) * OP3F + b;
    const float sm = op[0] + op[8] + op[16] + op[24];
    out[((size_t)(b0 + b) * TT + 0) * FF + gb] = sm + bo[gb];
  }
}

extern "C" void kernel_launch(void* const* d_in, const int* in_sizes, int n_in,
                              void* d_out, int out_size, void* d_ws, size_t ws_size,
                              hipStream_t stream) {
  const float* x    = (const float*)d_in[0];
  const float* eWih = (const float*)d_in[1];   // enc_Wih0 [2048,32]
  const float* eWhh = (const float*)d_in[2];   // enc_Whh0 [2048,512]
  const float* ebih = (const float*)d_in[3];
  const float* ebhh = (const float*)d_in[4];
  // d_in[5..8] enc layer 1: dead (only feeds dead decoder layer 1)
  const float* dWih = (const float*)d_in[9];   // dec_Wih0
  const float* dWhh = (const float*)d_in[10];  // dec_Whh0
  const float* dbih = (const float*)d_in[11];
  const float* dbhh = (const float*)d_in[12];
  // d_in[13..16] dec layer 1: dead (hB/cB never reach outs)
  const float* Wo   = (const float*)d_in[17];  // [32,512]
  const float* bo   = (const float*)d_in[18];  // [32]
  float* out = (float*)d_out;

  u64* pubbuf = (u64*)d_ws;                    // [2][PODS][BT][HH] tagged h

  hipFuncSetAttribute(reinterpret_cast<const void*>(lstm_ae_kernel),
                      hipFuncAttributeMaxDynamicSharedMemorySize, LDS_BYTES);

  init_ws_kernel<<<dim3((PUB_U64 + NTHR - 1) / NTHR), dim3(NTHR), 0, stream>>>(pubbuf);
  lstm_ae_kernel<<<dim3(NBLK), dim3(NTHR), LDS_BYTES, stream>>>(
      x, eWih, eWhh, ebih, ebhh, dWih, dWhh, dbih, dbhh, Wo, bo,
      out, pubbuf);
}